// Round 4
// baseline (1029.852 us; speedup 1.0000x reference)
//
#include <hip/hip_runtime.h>
#include <hip/hip_bf16.h>

// Bidirectional ConvLSTM, B=8 T=16 C=3 H=W=32 hid=64 K=7 ('SAME').
// Round 4: M split across BLOCKS (not waves) so all 4 waves of a block share
// the same A (weight) tile per K-step -> L1 broadcast, 4x less L2 A-traffic.
//   Block = (dir, b, ygrp 0..3, hb 0..3): M=64 oc (4 gates x 16 hid), N=256 px
//   (8 rows). Wave w handles rows Y0+2w, Y0+2w+1 (N=64 px, 4 16x16 tiles).
//   K = 105 steps of 32: ks 0..97 h-conv (k=ic chunk, (ky,kx,kc) via LDS LUT
//   offset), ks 98..104 x-conv (packed XB tile, kx via LUT offset).
// Dtype-adaptive (fp32 or bf16 inputs) via device flag, as round 2/3.
//
// Workspace (BYTE offsets), total 13,862,916 B:
//   hp0 : padded h ping, bf16 [dir][b][row38][col40][ic64] @ 0        (3,112,960)
//   hp1 : padded h pong                                    @ 3112960  (3,112,960)
//   c   : cell,  fp32 [dir][b][y32][x32][hid64]            @ 6225920  (4,194,304)
//   wall: bf16 [dir][hb4][ks105][g4][mi16][k32]            @ 10420224 (3,440,640)
//   bias: fp32 [dir][256]                                  @ 13860864 (2,048)
//   flag: int (1 = fp32 inputs)                            @ 13862912 (4)
//
// Dynamic LDS (shorts): h tile [14 rows][40 cols][72 icpad] @ 0      (40320)
//                       XB     [8 rows][40 cols][72 kpad]   @ 40320  (23040)
//                       LUT    105 ints                      @ 63360 (210)
//   total 63,570 shorts = 127,140 B (<= 160 KB/CU, 1 block/CU).

#define HP0_B  0
#define HP1_B  3112960
#define C_B    6225920
#define WALL_B 10420224
#define BIAS_B 13860864
#define FLAG_B 13862912

#define LDS_XB  40320
#define LDS_LUT 63360
#define LDS_SHORTS 63570

using short8 = __attribute__((ext_vector_type(8))) short;
using f32x4  = __attribute__((ext_vector_type(4))) float;

__device__ __forceinline__ float sigm(float x) { return 1.0f / (1.0f + __expf(-x)); }
__device__ __forceinline__ float tanh_f(float x) {
    x = fminf(fmaxf(x, -30.0f), 30.0f);
    float e = __expf(2.0f * x);
    return (e - 1.0f) / (e + 1.0f);
}

// ---- dtype probe (verified rounds 2-3) ----------------------------------
__global__ void detect_dtype(const unsigned int* __restrict__ xw, int* __restrict__ flag) {
    int lane = threadIdx.x;
    int cnt = 0;
    for (int i = 0; i < 4; ++i) {
        unsigned int w = xw[lane * 4 + i];
        unsigned int e = (w >> 7) & 0xFFu;
        cnt += (e >= 0xC0u) ? 1 : 0;
    }
#pragma unroll
    for (int off = 32; off > 0; off >>= 1) cnt += __shfl_down(cnt, off, 64);
    if (lane == 0) *flag = (cnt > 16) ? 1 : 0;
}

// ---- weights -> wall[d][hb][ks][g][mi][k32] bf16 + bias -----------------
__global__ void prep_weights(const void* __restrict__ whhf, const void* __restrict__ whhb,
                             const void* __restrict__ wihf, const void* __restrict__ wihb,
                             const void* __restrict__ bf, const void* __restrict__ bb,
                             short* __restrict__ wall, float* __restrict__ bias_r,
                             const int* __restrict__ flag) {
    int n = blockIdx.x * blockDim.x + threadIdx.x;
    const int fp32 = *flag;
    if (n < 1720320) {
        int k = n & 31;
        int mi = (n >> 5) & 15;
        int g = (n >> 9) & 3;
        int ks = (n >> 11) % 105;
        int hbq = (n >> 11) / 105; // 0..7 = d*4 + hb
        int hb = hbq & 3, d = hbq >> 2;
        int oc = g * 64 + hb * 16 + mi;
        const void* hh = d ? whhb : whhf;
        const void* ih = d ? wihb : wihf;
        float v = 0.0f;
        if (ks < 98) {
            int ky = ks / 14, rr = ks % 14, kc = rr / 7, kx = rr % 7;
            int si = ((oc * 64 + kc * 32 + k) * 7 + ky) * 7 + kx;
            v = fp32 ? ((const float*)hh)[si] : __bfloat162float(((const __hip_bfloat16*)hh)[si]);
        } else {
            int kx = ks - 98, ky = k >> 2, ic = k & 3;
            if (ic < 3 && ky < 7) {
                int si = ((oc * 3 + ic) * 7 + ky) * 7 + kx;
                v = fp32 ? ((const float*)ih)[si] : __bfloat162float(((const __hip_bfloat16*)ih)[si]);
            }
        }
        __hip_bfloat16 hv = __float2bfloat16(v);
        wall[n] = *(short*)&hv;
        return;
    }
    n -= 1720320;
    if (n < 512) {
        const void* src = (n >= 256) ? bb : bf;
        int j = n & 255;
        bias_r[n] = fp32 ? ((const float*)src)[j] : __bfloat162float(((const __hip_bfloat16*)src)[j]);
    }
}

// ---- zero hp0+hp1+c (contiguous 2,605,056 dwords at ws start) -----------
__global__ void zero_state(float* __restrict__ ws_f) {
    int n = blockIdx.x * blockDim.x + threadIdx.x;
    if (n < 2605056) ws_f[n] = 0.0f;
}

// ---- MFMA step kernel ----------------------------------------------------
// grid (16 = ygrp*? : x -> hb = x&3, ygrp = x>>2 ; 8 b, 2 dir), 256 thr.
__global__ __launch_bounds__(256, 1)
void lstm_step(const void* __restrict__ xin,
               const short* __restrict__ wall,
               const float* __restrict__ bias_r,
               const unsigned short* __restrict__ hp_r,
               unsigned short* __restrict__ hp_w,
               float* __restrict__ c,
               void* __restrict__ out,
               const int* __restrict__ flag, int s) {
    const int hb = blockIdx.x & 3;
    const int ygrp = blockIdx.x >> 2;
    const int b = blockIdx.y;
    const int dir = blockIdx.z;
    const int t = dir ? (15 - s) : s;
    const int Y0 = ygrp * 8;
    const int tid = threadIdx.x;
    const int w = tid >> 6;
    const int l = tid & 63;
    const int q = l >> 4;
    const int li = l & 15;
    const int fp32 = *flag;
    const int db = dir * 8 + b;

    extern __shared__ short lds[];
    int* lut = (int*)&lds[LDS_LUT];

    // offset LUT (shared by h-steps and x-steps; both tiles use stride 72)
    if (tid < 105) {
        int uoff;
        if (tid < 98) {
            int ky = tid / 14, rr = tid % 14, kc = rr / 7, kx = rr % 7;
            uoff = ky * 2880 + kx * 72 + kc * 32;
        } else {
            uoff = LDS_XB + (tid - 98) * 72;
        }
        lut[tid] = uoff;
    }

    // stage h rows Y0..Y0+13 (contiguous in global) into padded LDS
    {
        const uint4* src = (const uint4*)(hp_r + (size_t)(db * 38 + Y0) * 40 * 64);
        for (int i = tid; i < 4480; i += 256) {
            int ic8 = i & 7, col = (i >> 3) % 40, row = i / 320;
            uint4 v = src[i];
            *(uint4*)&lds[(row * 40 + col) * 72 + ic8 * 8] = v;
        }
    }
    // build XB[r8][cc40][k(0..31, stride 72)], k = ky*4+ic (28 used, 28..31 zero)
    for (int i = tid; i < 5120; i += 256) {
        int u = i & 15, cc = (i >> 4) % 40, r = i / 640;
        unsigned int pk = 0;
#pragma unroll
        for (int h2 = 0; h2 < 2; ++h2) {
            int k = 2 * u + h2;
            float v = 0.0f;
            if (k < 28) {
                int ky = k >> 2, ic = k & 3;
                int yin = Y0 + r + ky - 3, cin = cc - 3;
                if (ic < 3 && yin >= 0 && yin < 32 && cin >= 0 && cin < 32) {
                    size_t gi = (size_t)((b * 16 + t) * 3 + ic) * 1024 + yin * 32 + cin;
                    v = fp32 ? ((const float*)xin)[gi]
                             : __bfloat162float(((const __hip_bfloat16*)xin)[gi]);
                }
            }
            __hip_bfloat16 hv = __float2bfloat16(v);
            pk |= ((unsigned int)*(unsigned short*)&hv) << (16 * h2);
        }
        *(unsigned int*)&lds[LDS_XB + (r * 40 + cc) * 72 + 2 * u] = pk;
    }
    __syncthreads();

    // acc init from bias: C/D row = q*4+r -> hid = hb*16 + q*4 + r
    const int hid0 = hb * 16 + q * 4;
    f32x4 acc[4][4];
    {
        const float* bp = bias_r + dir * 256 + hid0;
#pragma unroll
        for (int g = 0; g < 4; ++g) {
            f32x4 bv = *(const f32x4*)(bp + g * 64);
#pragma unroll
            for (int nt = 0; nt < 4; ++nt) acc[g][nt] = bv;
        }
    }

    // lane bases: A shared by all 4 waves; B rows per-wave (yloc = 2w+rt)
    const short* wblk = wall + (size_t)(dir * 4 + hb) * 105 * 2048 + li * 32 + q * 8;
    int bnt[4];
#pragma unroll
    for (int nt = 0; nt < 4; ++nt)
        bnt[nt] = ((2 * w + (nt >> 1)) * 40 + (nt & 1) * 16 + li) * 72 + q * 8;

    auto loadA = [&](short8* A, int ks) {
        const short* p = wblk + (size_t)ks * 2048;
#pragma unroll
        for (int g = 0; g < 4; ++g) A[g] = *(const short8*)(p + g * 512);
    };
    auto loadB = [&](short8* B, int ks) {
        int uoff = lut[ks];
#pragma unroll
        for (int nt = 0; nt < 4; ++nt) B[nt] = *(const short8*)&lds[bnt[nt] + uoff];
    };
    auto mfma16 = [&](short8* A, short8* B) {
#pragma unroll
        for (int g = 0; g < 4; ++g)
#pragma unroll
            for (int nt = 0; nt < 4; ++nt)
                acc[g][nt] = __builtin_amdgcn_mfma_f32_16x16x32_bf16(A[g], B[nt], acc[g][nt], 0, 0, 0);
    };

    short8 A0[4], A1[4], B0[4], B1[4];
    loadA(A0, 0); loadB(B0, 0);
#pragma unroll 1
    for (int ks = 0; ks < 104; ks += 2) {
        loadA(A1, ks + 1); loadB(B1, ks + 1);
        mfma16(A0, B0);
        loadA(A0, ks + 2); loadB(B0, ks + 2);
        mfma16(A1, B1);
    }
    mfma16(A0, B0); // ks = 104

    // epilogue (in-wave: all 4 gates present)
#pragma unroll
    for (int nt = 0; nt < 4; ++nt) {
        int y = Y0 + 2 * w + (nt >> 1);
        int px = (nt & 1) * 16 + li;
        float* cp = c + (size_t)(db * 1024 + y * 32 + px) * 64 + hid0;
        f32x4 cold = *(const f32x4*)cp;
        f32x4 hv;
#pragma unroll
        for (int r = 0; r < 4; ++r) {
            float iv = sigm(acc[0][nt][r]);
            float fv = sigm(acc[1][nt][r]);
            float gv = tanh_f(acc[2][nt][r]);
            float ov = sigm(acc[3][nt][r]);
            float cn = fv * cold[r] + iv * gv;
            cold[r] = cn;
            hv[r] = ov * tanh_f(cn);
        }
        *(f32x4*)cp = cold;

        ushort4 hu;
        {
            __hip_bfloat16 t0 = __float2bfloat16(hv[0]); hu.x = *(unsigned short*)&t0;
            __hip_bfloat16 t1 = __float2bfloat16(hv[1]); hu.y = *(unsigned short*)&t1;
            __hip_bfloat16 t2 = __float2bfloat16(hv[2]); hu.z = *(unsigned short*)&t2;
            __hip_bfloat16 t3 = __float2bfloat16(hv[3]); hu.w = *(unsigned short*)&t3;
        }
        *(ushort4*)(hp_w + (size_t)((db * 38 + y + 3) * 40 + px + 3) * 64 + hid0) = hu;

        size_t ob = (size_t)((b * 16 + t) * 128 + dir * 64 + hid0) * 1024 + y * 32 + px;
        if (fp32) {
            float* op = (float*)out;
#pragma unroll
            for (int r = 0; r < 4; ++r) op[ob + (size_t)r * 1024] = hv[r];
        } else {
            __hip_bfloat16* op = (__hip_bfloat16*)out;
#pragma unroll
            for (int r = 0; r < 4; ++r) op[ob + (size_t)r * 1024] = __float2bfloat16(hv[r]);
        }
    }
}

extern "C" void kernel_launch(void* const* d_in, const int* in_sizes, int n_in,
                              void* d_out, int out_size, void* d_ws, size_t ws_size,
                              hipStream_t stream) {
    char* wsb = (char*)d_ws;
    unsigned short* hp0 = (unsigned short*)(wsb + HP0_B);
    unsigned short* hp1 = (unsigned short*)(wsb + HP1_B);
    float* c = (float*)(wsb + C_B);
    short* wall = (short*)(wsb + WALL_B);
    float* bias_r = (float*)(wsb + BIAS_B);
    int* flag = (int*)(wsb + FLAG_B);

    // inputs: 0=x 1=w_ih_f 2=w_hh_f 3=b_f 4=w_ih_b 5=w_hh_b 6=b_b
    detect_dtype<<<1, 64, 0, stream>>>((const unsigned int*)d_in[0], flag);
    prep_weights<<<6722, 256, 0, stream>>>(d_in[2], d_in[5], d_in[1], d_in[4],
                                           d_in[3], d_in[6], wall, bias_r, flag);
    zero_state<<<10176, 256, 0, stream>>>((float*)d_ws);

    const size_t shmem = LDS_SHORTS * sizeof(short); // 127,140 B
    for (int s = 0; s < 16; ++s) {
        unsigned short* hr = (s & 1) ? hp1 : hp0;
        unsigned short* hw = (s & 1) ? hp0 : hp1;
        lstm_step<<<dim3(16, 8, 2), 256, shmem, stream>>>(d_in[0], wall, bias_r,
                                                          hr, hw, c, d_out, flag, s);
    }
}

// Round 6
// 1029.813 us; speedup vs baseline: 1.0000x; 1.0000x over previous
//
#include <hip/hip_runtime.h>
#include <hip/hip_bf16.h>

// Bidirectional ConvLSTM, B=8 T=16 C=3 H=W=32 hid=64 K=7 ('SAME').
// Round 6 = round 5 with the prefetch-ring tail bug fixed (ks=101 was
// overwritten before use -> one missing x-conv K-step, absmax 1.15).
//  - Grid 512 (1-dim), block = M64 (4g x 16 hid) x N128 (4 rows x 32 cols);
//    4 waves, wave = 1 row (2 n-tiles). LDS 76.2 KB -> 2 blocks/CU, 8 waves.
//  - blockIdx bits[0:2] = dir*4+hb  -> each XCD sees ONE 430 KB wall slice
//    (L2-resident across all 16 steps).
//  - 4-deep software prefetch ring for A (global) and B (LDS).
//  - LDS pad 68 shorts (34 dwords, 2-way max -> free).
// Dtype-adaptive (fp32 or bf16 inputs) via device flag, as rounds 2-5.
//
// Workspace (BYTE offsets), total 13,862,916 B:
//   hp0 : padded h ping, bf16 [dir][b][row38][col40][ic64] @ 0        (3,112,960)
//   hp1 : padded h pong                                    @ 3112960  (3,112,960)
//   c   : cell,  fp32 [dir][b][y32][x32][hid64]            @ 6225920  (4,194,304)
//   wall: bf16 [dir][hb4][ks105][g4][mi16][k32]            @ 10420224 (3,440,640)
//   bias: fp32 [dir][256]                                  @ 13860864 (2,048)
//   flag: int (1 = fp32 inputs)                            @ 13862912 (4)

#define HP0_B  0
#define HP1_B  3112960
#define C_B    6225920
#define WALL_B 10420224
#define BIAS_B 13860864
#define FLAG_B 13862912

#define ICP   68          // padded inner stride (shorts)
#define RSTR  (40 * ICP)  // row stride = 2720 shorts
#define XBOFF (10 * RSTR) // 27200 shorts
#define LDS_SHORTS (XBOFF + 4 * RSTR) // 38080

using short8 = __attribute__((ext_vector_type(8))) short;
using f32x4  = __attribute__((ext_vector_type(4))) float;

__device__ __forceinline__ float sigm(float x) { return 1.0f / (1.0f + __expf(-x)); }
__device__ __forceinline__ float tanh_f(float x) {
    x = fminf(fmaxf(x, -30.0f), 30.0f);
    float e = __expf(2.0f * x);
    return (e - 1.0f) / (e + 1.0f);
}

// ---- dtype probe (verified rounds 2-5) ----------------------------------
__global__ void detect_dtype(const unsigned int* __restrict__ xw, int* __restrict__ flag) {
    int lane = threadIdx.x;
    int cnt = 0;
    for (int i = 0; i < 4; ++i) {
        unsigned int w = xw[lane * 4 + i];
        unsigned int e = (w >> 7) & 0xFFu;
        cnt += (e >= 0xC0u) ? 1 : 0;
    }
#pragma unroll
    for (int off = 32; off > 0; off >>= 1) cnt += __shfl_down(cnt, off, 64);
    if (lane == 0) *flag = (cnt > 16) ? 1 : 0;
}

// ---- weights -> wall[d][hb][ks][g][mi][k32] bf16 + bias -----------------
__global__ void prep_weights(const void* __restrict__ whhf, const void* __restrict__ whhb,
                             const void* __restrict__ wihf, const void* __restrict__ wihb,
                             const void* __restrict__ bf, const void* __restrict__ bb,
                             short* __restrict__ wall, float* __restrict__ bias_r,
                             const int* __restrict__ flag) {
    int n = blockIdx.x * blockDim.x + threadIdx.x;
    const int fp32 = *flag;
    if (n < 1720320) {
        int k = n & 31;
        int mi = (n >> 5) & 15;
        int g = (n >> 9) & 3;
        int ks = (n >> 11) % 105;
        int hbq = (n >> 11) / 105; // 0..7 = d*4 + hb
        int hb = hbq & 3, d = hbq >> 2;
        int oc = g * 64 + hb * 16 + mi;
        const void* hh = d ? whhb : whhf;
        const void* ih = d ? wihb : wihf;
        float v = 0.0f;
        if (ks < 98) {
            int ky = ks / 14, rr = ks % 14, kc = rr / 7, kx = rr % 7;
            int si = ((oc * 64 + kc * 32 + k) * 7 + ky) * 7 + kx;
            v = fp32 ? ((const float*)hh)[si] : __bfloat162float(((const __hip_bfloat16*)hh)[si]);
        } else {
            int kx = ks - 98, ky = k >> 2, ic = k & 3;
            if (ic < 3 && ky < 7) {
                int si = ((oc * 3 + ic) * 7 + ky) * 7 + kx;
                v = fp32 ? ((const float*)ih)[si] : __bfloat162float(((const __hip_bfloat16*)ih)[si]);
            }
        }
        __hip_bfloat16 hv = __float2bfloat16(v);
        wall[n] = *(short*)&hv;
        return;
    }
    n -= 1720320;
    if (n < 512) {
        const void* src = (n >= 256) ? bb : bf;
        int j = n & 255;
        bias_r[n] = fp32 ? ((const float*)src)[j] : __bfloat162float(((const __hip_bfloat16*)src)[j]);
    }
}

// ---- zero hp0+hp1+c (contiguous 2,605,056 dwords at ws start) -----------
__global__ void zero_state(float* __restrict__ ws_f) {
    int n = blockIdx.x * blockDim.x + threadIdx.x;
    if (n < 2605056) ws_f[n] = 0.0f;
}

// ---- B-tile LDS offset for K-step ks (wave-uniform scalar math) ---------
__device__ __forceinline__ int uoff_of(int ks) {
    if (ks < 98) {
        int ky = ks / 14, rr = ks - 14 * ky;
        int kc = rr / 7, kx = rr - 7 * kc;
        return ky * RSTR + kx * ICP + kc * 32;
    }
    return XBOFF + (ks - 98) * ICP;
}

// ---- MFMA step kernel ----------------------------------------------------
// grid 512 x 256 thr. blockIdx bits: [0:2]=(dir*4+hb), [3:5]=b, [6:8]=ygrp.
// Block: M=64 oc, rows Y0..Y0+3. Wave w = row Y0+w.
__global__ __launch_bounds__(256, 2)
void lstm_step(const void* __restrict__ xin,
               const short* __restrict__ wall,
               const float* __restrict__ bias_r,
               const unsigned short* __restrict__ hp_r,
               unsigned short* __restrict__ hp_w,
               float* __restrict__ c,
               void* __restrict__ out,
               const int* __restrict__ flag, int s) {
    const int lin = blockIdx.x;
    const int hb = lin & 3;
    const int dir = (lin >> 2) & 1;
    const int b = (lin >> 3) & 7;
    const int ygrp = lin >> 6;
    const int t = dir ? (15 - s) : s;
    const int Y0 = ygrp * 4;
    const int tid = threadIdx.x;
    const int w = tid >> 6;
    const int l = tid & 63;
    const int q = l >> 4;
    const int li = l & 15;
    const int fp32 = *flag;
    const int db = dir * 8 + b;

    extern __shared__ short lds[];

    // stage h rows Y0..Y0+9 (contiguous in global) into padded LDS
    {
        const uint4* src = (const uint4*)(hp_r + (size_t)(db * 38 + Y0) * 40 * 64);
        for (int i = tid; i < 3200; i += 256) {
            int ic8 = i & 7, col = (i >> 3) % 40, row = i / 320;
            uint4 v = src[i];
            *(uint4*)&lds[(row * 40 + col) * ICP + ic8 * 8] = v;
        }
    }
    // build XB[r4][cc40][k32 in 68-pad], k = ky*4+ic (28 used, 28..31 zero)
    for (int i = tid; i < 2560; i += 256) {
        int u = i & 15, cc = (i >> 4) % 40, r = i / 640;
        unsigned int pk = 0;
#pragma unroll
        for (int h2 = 0; h2 < 2; ++h2) {
            int k = 2 * u + h2;
            float v = 0.0f;
            if (k < 28) {
                int ky = k >> 2, ic = k & 3;
                int yin = Y0 + r + ky - 3, cin = cc - 3;
                if (ic < 3 && yin >= 0 && yin < 32 && cin >= 0 && cin < 32) {
                    size_t gi = (size_t)((b * 16 + t) * 3 + ic) * 1024 + yin * 32 + cin;
                    v = fp32 ? ((const float*)xin)[gi]
                             : __bfloat162float(((const __hip_bfloat16*)xin)[gi]);
                }
            }
            __hip_bfloat16 hv = __float2bfloat16(v);
            pk |= ((unsigned int)*(unsigned short*)&hv) << (16 * h2);
        }
        *(unsigned int*)&lds[XBOFF + (r * 40 + cc) * ICP + 2 * u] = pk;
    }
    __syncthreads();

    // acc init from bias: C/D row = q*4+r -> hid = hb*16 + q*4 + r
    const int hid0 = hb * 16 + q * 4;
    f32x4 acc[4][2];
    {
        const float* bp = bias_r + dir * 256 + hid0;
#pragma unroll
        for (int g = 0; g < 4; ++g) {
            f32x4 bv = *(const f32x4*)(bp + g * 64);
            acc[g][0] = bv;
            acc[g][1] = bv;
        }
    }

    // lane bases
    const short* wblk = wall + (size_t)(dir * 4 + hb) * 105 * 2048 + li * 32 + q * 8;
    const int bq = w * RSTR + li * ICP + q * 8; // + nt*16*ICP + uoff(ks)

    auto loadA = [&](short8* A, int ks) {
        const short* p = wblk + (size_t)ks * 2048;
#pragma unroll
        for (int g = 0; g < 4; ++g) A[g] = *(const short8*)(p + g * 512);
    };
    auto loadB = [&](short8* B, int ks) {
        int uo = bq + uoff_of(ks);
        B[0] = *(const short8*)&lds[uo];
        B[1] = *(const short8*)&lds[uo + 16 * ICP];
    };
    auto mfma8 = [&](short8* A, short8* B) {
#pragma unroll
        for (int g = 0; g < 4; ++g)
#pragma unroll
            for (int nt = 0; nt < 2; ++nt)
                acc[g][nt] = __builtin_amdgcn_mfma_f32_16x16x32_bf16(A[g], B[nt], acc[g][nt], 0, 0, 0);
    };

    // 4-deep prefetch ring over 105 K-steps
    short8 Ar[4][4], Br[4][2];
#pragma unroll
    for (int j = 0; j < 4; ++j) { loadA(Ar[j], j); loadB(Br[j], j); }

    // 25 groups: process ks 0..99, prefetch up to ks 103
#pragma unroll 1
    for (int qq = 0; qq < 25; ++qq) {
        int ks = 4 * qq;
#pragma unroll
        for (int j = 0; j < 4; ++j) {
            mfma8(Ar[j], Br[j]);
            loadA(Ar[j], ks + 4 + j);
            loadB(Br[j], ks + 4 + j);
        }
    }
    // slots hold ks 100..103; consume each exactly once, slot0 reused for 104
    mfma8(Ar[0], Br[0]); loadA(Ar[0], 104); loadB(Br[0], 104); // ks 100
    mfma8(Ar[1], Br[1]);                                        // ks 101
    mfma8(Ar[2], Br[2]);                                        // ks 102
    mfma8(Ar[3], Br[3]);                                        // ks 103
    mfma8(Ar[0], Br[0]);                                        // ks 104

    // epilogue (in-wave: all 4 gates present); wave row y = Y0 + w
    const int y = Y0 + w;
#pragma unroll
    for (int nt = 0; nt < 2; ++nt) {
        int px = nt * 16 + li;
        float* cp = c + (size_t)(db * 1024 + y * 32 + px) * 64 + hid0;
        f32x4 cold = *(const f32x4*)cp;
        f32x4 hv;
#pragma unroll
        for (int r = 0; r < 4; ++r) {
            float iv = sigm(acc[0][nt][r]);
            float fv = sigm(acc[1][nt][r]);
            float gv = tanh_f(acc[2][nt][r]);
            float ov = sigm(acc[3][nt][r]);
            float cn = fv * cold[r] + iv * gv;
            cold[r] = cn;
            hv[r] = ov * tanh_f(cn);
        }
        *(f32x4*)cp = cold;

        ushort4 hu;
        {
            __hip_bfloat16 t0 = __float2bfloat16(hv[0]); hu.x = *(unsigned short*)&t0;
            __hip_bfloat16 t1 = __float2bfloat16(hv[1]); hu.y = *(unsigned short*)&t1;
            __hip_bfloat16 t2 = __float2bfloat16(hv[2]); hu.z = *(unsigned short*)&t2;
            __hip_bfloat16 t3 = __float2bfloat16(hv[3]); hu.w = *(unsigned short*)&t3;
        }
        *(ushort4*)(hp_w + (size_t)((db * 38 + y + 3) * 40 + px + 3) * 64 + hid0) = hu;

        size_t ob = (size_t)((b * 16 + t) * 128 + dir * 64 + hid0) * 1024 + y * 32 + px;
        if (fp32) {
            float* op = (float*)out;
#pragma unroll
            for (int r = 0; r < 4; ++r) op[ob + (size_t)r * 1024] = hv[r];
        } else {
            __hip_bfloat16* op = (__hip_bfloat16*)out;
#pragma unroll
            for (int r = 0; r < 4; ++r) op[ob + (size_t)r * 1024] = __float2bfloat16(hv[r]);
        }
    }
}

extern "C" void kernel_launch(void* const* d_in, const int* in_sizes, int n_in,
                              void* d_out, int out_size, void* d_ws, size_t ws_size,
                              hipStream_t stream) {
    char* wsb = (char*)d_ws;
    unsigned short* hp0 = (unsigned short*)(wsb + HP0_B);
    unsigned short* hp1 = (unsigned short*)(wsb + HP1_B);
    float* c = (float*)(wsb + C_B);
    short* wall = (short*)(wsb + WALL_B);
    float* bias_r = (float*)(wsb + BIAS_B);
    int* flag = (int*)(wsb + FLAG_B);

    // inputs: 0=x 1=w_ih_f 2=w_hh_f 3=b_f 4=w_ih_b 5=w_hh_b 6=b_b
    detect_dtype<<<1, 64, 0, stream>>>((const unsigned int*)d_in[0], flag);
    prep_weights<<<6722, 256, 0, stream>>>(d_in[2], d_in[5], d_in[1], d_in[4],
                                           d_in[3], d_in[6], wall, bias_r, flag);
    zero_state<<<10176, 256, 0, stream>>>((float*)d_ws);

    const size_t shmem = LDS_SHORTS * sizeof(short); // 76,160 B -> 2 blocks/CU
    for (int s = 0; s < 16; ++s) {
        unsigned short* hr = (s & 1) ? hp1 : hp0;
        unsigned short* hw = (s & 1) ? hp0 : hp1;
        lstm_step<<<512, 256, shmem, stream>>>(d_in[0], wall, bias_r,
                                               hr, hw, c, d_out, flag, s);
    }
}